// Round 1
// baseline (672.730 us; speedup 1.0000x reference)
//
#include <hip/hip_runtime.h>

// NonLocalBlockND: B=8, C=256, CI=128, H=W=64. All fp32.
// out = BN(conv_w( attn(theta(x), pool(phi(x)), pool(g(x))) )) + x
//
// ws layout (floats):
//   theta : [8,128,4096]  @ 0          (4,194,304)
//   tmp   : [8,128,4096]  @ 4194304    (4,194,304)  full conv before pooling
//   phi_p : [8,128,1024]  @ 8388608    (1,048,576)
//   g_p   : [8,128,1024]  @ 9437184    (1,048,576)
//   ybuf  : [8,128,4096]  @ 10485760   (4,194,304)
// total 14,680,064 floats = 56 MiB

constexpr int Bn = 8;
constexpr int Cc = 256;
constexpr int Ci = 128;
constexpr int Hh = 64;
constexpr int Wh = 64;
constexpr int Nn = Hh * Wh;              // 4096
constexpr int Mm = (Hh / 2) * (Wh / 2);  // 1024
constexpr float kEps = 1e-5f;

// ---------------------------------------------------------------------------
// conv1x1: out[b,o,n] = sum_c W[o,c]*xin[b,c,n] + bias[o]
// FINAL variant fuses BN + residual: ((acc+bias)-mean)*gamma*rsqrt(var+eps)+beta+x
// Block = 256 threads computes an [O x 64] tile for one (b, n-tile).
// Thread owns 2 consecutive n, NO=O/8 outputs o.
// ---------------------------------------------------------------------------
template <int O, int K, bool FINAL>
__global__ __launch_bounds__(256) void conv1x1_kernel(
    const float* __restrict__ xin, const float* __restrict__ Wt,
    const float* __restrict__ bias, float* __restrict__ out,
    const float* __restrict__ resid, const float* __restrict__ gamma,
    const float* __restrict__ beta, const float* __restrict__ mean,
    const float* __restrict__ var) {
  constexpr int NO = O / 8;  // outputs per thread (16 or 32)
  __shared__ float xs[64][64];  // [c][n] chunk
  __shared__ float wsT[64][O];  // [c][o], o-index XOR-swizzled by ((c&7)<<2)

  const int b = blockIdx.y;
  const int n0 = blockIdx.x * 64;
  const int tid = threadIdx.x;
  const int nl = (tid & 31) * 2;       // local n pair
  const int o0 = (tid >> 5) * NO;      // o base

  float acc0[NO], acc1[NO];
#pragma unroll
  for (int j = 0; j < NO; ++j) {
    acc0[j] = 0.f;
    acc1[j] = 0.f;
  }

  const float* xb = xin + (size_t)b * K * Nn + n0;

  for (int c0 = 0; c0 < K; c0 += 64) {
    __syncthreads();
    {
      const int n = tid & 63, cg = tid >> 6;
#pragma unroll
      for (int i = 0; i < 16; ++i) {
        const int c = cg * 16 + i;
        xs[c][n] = xb[(size_t)(c0 + c) * Nn + n];
      }
      const int cc = tid & 63, og = tid >> 6;
#pragma unroll
      for (int i = 0; i < O / 4; ++i) {
        const int o = og * (O / 4) + i;
        wsT[cc][o ^ ((cc & 7) << 2)] = Wt[(size_t)o * K + (c0 + cc)];
      }
    }
    __syncthreads();
#pragma unroll 4
    for (int cc = 0; cc < 64; ++cc) {
      const float2 xv = *(const float2*)&xs[cc][nl];
      const int sw = (cc & 7) << 2;
#pragma unroll
      for (int jq = 0; jq < NO / 4; ++jq) {
        const float4 wv = *(const float4*)&wsT[cc][(o0 + jq * 4) ^ sw];
        acc0[jq * 4 + 0] = fmaf(wv.x, xv.x, acc0[jq * 4 + 0]);
        acc0[jq * 4 + 1] = fmaf(wv.y, xv.x, acc0[jq * 4 + 1]);
        acc0[jq * 4 + 2] = fmaf(wv.z, xv.x, acc0[jq * 4 + 2]);
        acc0[jq * 4 + 3] = fmaf(wv.w, xv.x, acc0[jq * 4 + 3]);
        acc1[jq * 4 + 0] = fmaf(wv.x, xv.y, acc1[jq * 4 + 0]);
        acc1[jq * 4 + 1] = fmaf(wv.y, xv.y, acc1[jq * 4 + 1]);
        acc1[jq * 4 + 2] = fmaf(wv.z, xv.y, acc1[jq * 4 + 2]);
        acc1[jq * 4 + 3] = fmaf(wv.w, xv.y, acc1[jq * 4 + 3]);
      }
    }
  }

  float* ob = out + (size_t)b * O * Nn + n0 + nl;
  if (!FINAL) {
#pragma unroll
    for (int j = 0; j < NO; ++j) {
      const int o = o0 + j;
      const float bv = bias[o];
      float2 v;
      v.x = acc0[j] + bv;
      v.y = acc1[j] + bv;
      *(float2*)&ob[(size_t)o * Nn] = v;
    }
  } else {
    const float* xr = resid + (size_t)b * O * Nn + n0 + nl;
#pragma unroll
    for (int j = 0; j < NO; ++j) {
      const int o = o0 + j;
      const float sc = gamma[o] * rsqrtf(var[o] + kEps);
      const float sh = beta[o] + (bias[o] - mean[o]) * sc;
      const float2 xv = *(const float2*)&xr[(size_t)o * Nn];
      float2 v;
      v.x = fmaf(acc0[j], sc, sh) + xv.x;
      v.y = fmaf(acc1[j], sc, sh) + xv.y;
      *(float2*)&ob[(size_t)o * Nn] = v;
    }
  }
}

// ---------------------------------------------------------------------------
// 2x2 max pool, stride 2 (per [b,ci] plane of 64x64 -> 32x32)
// ---------------------------------------------------------------------------
__global__ __launch_bounds__(256) void pool_kernel(const float* __restrict__ in,
                                                   float* __restrict__ out) {
  const int t = blockIdx.x * 256 + threadIdx.x;  // 0 .. B*Ci*Mm-1
  const int wm = t & 31;
  const int hm = (t >> 5) & 31;
  const int bc = t >> 10;  // b*Ci + ci
  const float* p = in + (size_t)bc * Nn + (size_t)(hm * 2) * Wh + wm * 2;
  out[t] = fmaxf(fmaxf(p[0], p[1]), fmaxf(p[Wh], p[Wh + 1]));
}

// ---------------------------------------------------------------------------
// Fused attention: y[b,ci,n] = (1/M) * sum_m (sum_c th[c,n]*ph[c,m]) * g[ci,m]
// Block = 512 threads handles one (b, 64-wide n-tile); loops 64-wide m-tiles.
// Never materializes f. S stored transposed (ST[m][n]) to keep reads stride-1.
// ---------------------------------------------------------------------------
__global__ __launch_bounds__(512) void attn_kernel(
    const float* __restrict__ theta, const float* __restrict__ phi,
    const float* __restrict__ g, float* __restrict__ y) {
  __shared__ float th[Ci][64];       // [ci][n]
  __shared__ float ph[Ci][64];       // [ci][m]
  __shared__ float gsT[64][Ci + 4];  // [m][ci] padded
  __shared__ float ST[64][68];       // [m][n] padded

  const int b = blockIdx.y;
  const int n0 = blockIdx.x * 64;
  const int tid = threadIdx.x;
  const int nq = (tid & 15) * 4;   // 4 n's (both phases)
  const int mq = (tid >> 4) * 2;   // 2 m's (S phase), 0..62
  const int cib = (tid >> 4) * 4;  // 4 ci's (Y phase), 0..124

  {
    const int n = tid & 63, cg = tid >> 6;
#pragma unroll
    for (int i = 0; i < 16; ++i) {
      const int ci = cg * 16 + i;
      th[ci][n] = theta[((size_t)b * Ci + ci) * Nn + n0 + n];
    }
  }

  float acc[4][4];  // [ci][n]
#pragma unroll
  for (int j = 0; j < 4; ++j)
#pragma unroll
    for (int k = 0; k < 4; ++k) acc[j][k] = 0.f;

  for (int m0 = 0; m0 < Mm; m0 += 64) {
    __syncthreads();  // protect ph/gsT/ST from previous iteration's readers
    {
      const int mm = tid & 63, cg = tid >> 6;
#pragma unroll
      for (int i = 0; i < 16; ++i) {
        const int ci = cg * 16 + i;
        const size_t idx = ((size_t)b * Ci + ci) * Mm + m0 + mm;
        ph[ci][mm] = phi[idx];
        gsT[mm][ci] = g[idx];
      }
    }
    __syncthreads();

    // S phase: S[n,m] = sum_ci th[ci][n]*ph[ci][m]; thread does 4n x 2m
    float s0[4], s1[4];
#pragma unroll
    for (int k = 0; k < 4; ++k) {
      s0[k] = 0.f;
      s1[k] = 0.f;
    }
#pragma unroll 4
    for (int ci = 0; ci < Ci; ++ci) {
      const float4 tv = *(const float4*)&th[ci][nq];
      const float2 pv = *(const float2*)&ph[ci][mq];
      s0[0] = fmaf(pv.x, tv.x, s0[0]);
      s0[1] = fmaf(pv.x, tv.y, s0[1]);
      s0[2] = fmaf(pv.x, tv.z, s0[2]);
      s0[3] = fmaf(pv.x, tv.w, s0[3]);
      s1[0] = fmaf(pv.y, tv.x, s1[0]);
      s1[1] = fmaf(pv.y, tv.y, s1[1]);
      s1[2] = fmaf(pv.y, tv.z, s1[2]);
      s1[3] = fmaf(pv.y, tv.w, s1[3]);
    }
    *(float4*)&ST[mq][nq] = make_float4(s0[0], s0[1], s0[2], s0[3]);
    *(float4*)&ST[mq + 1][nq] = make_float4(s1[0], s1[1], s1[2], s1[3]);
    __syncthreads();

    // Y phase: acc[ci][n] += g[ci][m] * S[n][m]; thread does 4ci x 4n
#pragma unroll 4
    for (int mm = 0; mm < 64; ++mm) {
      const float4 sv = *(const float4*)&ST[mm][nq];
      const float4 gv = *(const float4*)&gsT[mm][cib];
      acc[0][0] = fmaf(gv.x, sv.x, acc[0][0]);
      acc[0][1] = fmaf(gv.x, sv.y, acc[0][1]);
      acc[0][2] = fmaf(gv.x, sv.z, acc[0][2]);
      acc[0][3] = fmaf(gv.x, sv.w, acc[0][3]);
      acc[1][0] = fmaf(gv.y, sv.x, acc[1][0]);
      acc[1][1] = fmaf(gv.y, sv.y, acc[1][1]);
      acc[1][2] = fmaf(gv.y, sv.z, acc[1][2]);
      acc[1][3] = fmaf(gv.y, sv.w, acc[1][3]);
      acc[2][0] = fmaf(gv.z, sv.x, acc[2][0]);
      acc[2][1] = fmaf(gv.z, sv.y, acc[2][1]);
      acc[2][2] = fmaf(gv.z, sv.z, acc[2][2]);
      acc[2][3] = fmaf(gv.z, sv.w, acc[2][3]);
      acc[3][0] = fmaf(gv.w, sv.x, acc[3][0]);
      acc[3][1] = fmaf(gv.w, sv.y, acc[3][1]);
      acc[3][2] = fmaf(gv.w, sv.z, acc[3][2]);
      acc[3][3] = fmaf(gv.w, sv.w, acc[3][3]);
    }
  }

  constexpr float scale = 1.f / (float)Mm;
#pragma unroll
  for (int j = 0; j < 4; ++j) {
    float4 v;
    v.x = acc[j][0] * scale;
    v.y = acc[j][1] * scale;
    v.z = acc[j][2] * scale;
    v.w = acc[j][3] * scale;
    *(float4*)&y[((size_t)b * Ci + cib + j) * Nn + n0 + nq] = v;
  }
}

// ---------------------------------------------------------------------------
extern "C" void kernel_launch(void* const* d_in, const int* in_sizes, int n_in,
                              void* d_out, int out_size, void* d_ws,
                              size_t ws_size, hipStream_t stream) {
  const float* x = (const float*)d_in[0];
  const float* w_theta = (const float*)d_in[1];
  const float* b_theta = (const float*)d_in[2];
  const float* w_phi = (const float*)d_in[3];
  const float* b_phi = (const float*)d_in[4];
  const float* w_g = (const float*)d_in[5];
  const float* b_g = (const float*)d_in[6];
  const float* w_w = (const float*)d_in[7];
  const float* b_w = (const float*)d_in[8];
  const float* bn_gamma = (const float*)d_in[9];
  const float* bn_beta = (const float*)d_in[10];
  const float* bn_mean = (const float*)d_in[11];
  const float* bn_var = (const float*)d_in[12];
  float* out = (float*)d_out;

  float* ws = (float*)d_ws;
  float* theta = ws;                  // 4,194,304 floats
  float* tmp = ws + 4194304;          // 4,194,304
  float* phi_p = ws + 8388608;        // 1,048,576
  float* g_p = ws + 9437184;          // 1,048,576
  float* ybuf = ws + 10485760;        // 4,194,304
  if (ws_size < 14680064ull * sizeof(float)) return;  // need 56 MiB scratch

  const dim3 grid(Nn / 64, Bn);
  const dim3 blk(256);

  // theta = conv_theta(x)
  conv1x1_kernel<Ci, Cc, false><<<grid, blk, 0, stream>>>(
      x, w_theta, b_theta, theta, nullptr, nullptr, nullptr, nullptr, nullptr);
  // phi_p = pool(conv_phi(x))
  conv1x1_kernel<Ci, Cc, false><<<grid, blk, 0, stream>>>(
      x, w_phi, b_phi, tmp, nullptr, nullptr, nullptr, nullptr, nullptr);
  pool_kernel<<<dim3(Bn * Ci * Mm / 256), blk, 0, stream>>>(tmp, phi_p);
  // g_p = pool(conv_g(x))
  conv1x1_kernel<Ci, Cc, false><<<grid, blk, 0, stream>>>(
      x, w_g, b_g, tmp, nullptr, nullptr, nullptr, nullptr, nullptr);
  pool_kernel<<<dim3(Bn * Ci * Mm / 256), blk, 0, stream>>>(tmp, g_p);
  // ybuf = attention(theta, phi_p, g_p)
  attn_kernel<<<dim3(Nn / 64, Bn), dim3(512), 0, stream>>>(theta, phi_p, g_p,
                                                           ybuf);
  // out = BN(conv_w(ybuf)) + x
  conv1x1_kernel<Cc, Ci, true><<<grid, blk, 0, stream>>>(
      ybuf, w_w, b_w, out, x, bn_gamma, bn_beta, bn_mean, bn_var);
}

// Round 2
// 164.955 us; speedup vs baseline: 4.0783x; 4.0783x over previous
//
#include <hip/hip_runtime.h>

// NonLocalBlockND bf16-MFMA pipeline. B=8, C=256, CI=128, H=W=64.
// out = BN(conv_w( attn(theta(x), pool(phi(x)), pool(g(x))) )) + x
//
// ws layout (bytes):
//   xT     [8][4096][256] bf16 @ 0          (16,777,216)   x transposed, K-contig
//   thetaT [8][4096][128] bf16 @ 16777216   ( 8,388,608)
//   phiT   [8][1024][128] bf16 @ 25165824   ( 2,097,152)   pooled, [m][ci]
//   gP     [8][128][1024] bf16 @ 27262976   ( 2,097,152)   pooled, [ci][m]
//   yT     [8][4096][128] bf16 @ 29360128   ( 8,388,608)
//   W3b    [384][256]     bf16 @ 37748736   (   196,608)   theta/phi/g stacked
//   Wwb    [256][128]     bf16 @ 37945344   (    65,536)
// total 38,010,880 B

typedef __attribute__((ext_vector_type(8))) short bf16x8;
typedef __attribute__((ext_vector_type(4))) float f32x4;
typedef unsigned short u16;
typedef unsigned int u32;

constexpr int Bn = 8, Cc = 256, CiC = 128, NnC = 4096, MmC = 1024;
constexpr float kEps = 1e-5f;

__device__ __forceinline__ u16 f2b(float f) {
  u32 u = __float_as_uint(f);
  return (u16)((u + 0x7fffu + ((u >> 16) & 1u)) >> 16);
}
__device__ __forceinline__ float b2f(u16 h) {
  return __uint_as_float(((u32)h) << 16);
}
__device__ __forceinline__ u32 pack2(float a, float b) {
  return (u32)f2b(a) | ((u32)f2b(b) << 16);
}
__device__ __forceinline__ void gl16(const void* g, void* l) {
  __builtin_amdgcn_global_load_lds(
      (const __attribute__((address_space(1))) void*)g,
      (__attribute__((address_space(3))) void*)l, 16, 0, 0);
}

// ---------------------------------------------------------------------------
// prep_w: stack+convert conv weights to bf16.
// ---------------------------------------------------------------------------
__global__ __launch_bounds__(256) void prepw_kernel(
    const float* __restrict__ wt, const float* __restrict__ wp,
    const float* __restrict__ wg, const float* __restrict__ ww,
    u16* __restrict__ W3b, u16* __restrict__ Wwb) {
  const int idx = blockIdx.x * 256 + threadIdx.x;  // grid 512*256 = 131072
  if (idx < 98304) {
    const int r = idx >> 8, c = idx & 255;
    const float v = (r < 128)   ? wt[r * 256 + c]
                    : (r < 256) ? wp[(r - 128) * 256 + c]
                                : wg[(r - 256) * 256 + c];
    W3b[idx] = f2b(v);
  } else {
    const int j = idx - 98304;
    Wwb[j] = f2b(ww[j]);
  }
}

// ---------------------------------------------------------------------------
// prep_x: transpose x [b][c][n] f32 -> xT [b][n][c] bf16 via LDS tile.
// ---------------------------------------------------------------------------
__global__ __launch_bounds__(256) void prepx_kernel(const float* __restrict__ x,
                                                    u16* __restrict__ xT) {
  __shared__ float sm[64][65];
  const int b = blockIdx.z, c0 = blockIdx.y * 64, n0 = blockIdx.x * 64;
  const int tid = threadIdx.x;
  {
    const int n = tid & 63, cg = tid >> 6;
#pragma unroll
    for (int i = 0; i < 16; ++i) {
      const int c = cg * 16 + i;
      sm[c][n] = x[((size_t)(b * Cc + c0 + c)) * NnC + n0 + n];
    }
  }
  __syncthreads();
  {
    const int n = tid >> 2, q = tid & 3;
    u16 v[16];
#pragma unroll
    for (int j = 0; j < 16; ++j) v[j] = f2b(sm[q * 16 + j][n]);
    uint4 o0, o1;
    o0.x = v[0] | ((u32)v[1] << 16);
    o0.y = v[2] | ((u32)v[3] << 16);
    o0.z = v[4] | ((u32)v[5] << 16);
    o0.w = v[6] | ((u32)v[7] << 16);
    o1.x = v[8] | ((u32)v[9] << 16);
    o1.y = v[10] | ((u32)v[11] << 16);
    o1.z = v[12] | ((u32)v[13] << 16);
    o1.w = v[14] | ((u32)v[15] << 16);
    uint4* dst = (uint4*)(xT + ((size_t)(b * NnC + n0 + n)) * Cc + c0 + q * 16);
    dst[0] = o0;
    dst[1] = o1;
  }
}

// ---------------------------------------------------------------------------
// conv3: D[o][n] = W3b[mt*128+o][:] . xT[n][:] (K=256), 128x128 tile, 4 waves.
// Epilogue per mt: 0 -> thetaT[n][o] (transposed write via LDS bounce)
//                  1 -> phiT[m][ci] pooled   2 -> gP[ci][m] pooled
// ---------------------------------------------------------------------------
__global__ __launch_bounds__(256) void conv3_kernel(
    const u16* __restrict__ xT, const u16* __restrict__ W3b,
    const float* __restrict__ b_theta, const float* __restrict__ b_phi,
    const float* __restrict__ b_g, u16* __restrict__ thetaT,
    u16* __restrict__ phiT, u16* __restrict__ gP) {
  __shared__ u16 sm[2][2][8192];  // [buf][A/B][128 rows][64 k] bf16, 16KB each
  const int mt = blockIdx.x, nt = blockIdx.y, b = blockIdx.z;
  const int n0 = nt * 128;
  const int tid = threadIdx.x;
  const int w = tid >> 6, lane = tid & 63;
  const int r16 = lane & 15, kg = lane >> 4;
  const int oh = (w & 1) * 64, nh = (w >> 1) * 64;

  auto stage = [&](int buf, int k0) {
#pragma unroll
    for (int i = 0; i < 4; ++i) {
      const int lin = i * 4096 + tid * 16;
      const int row = lin >> 7, byte = lin & 127;
      gl16((const char*)W3b + (size_t)(mt * 128 + row) * 512 + k0 * 2 +
               (byte ^ ((row & 7) << 4)),
           (char*)&sm[buf][0][0] + lin);
    }
#pragma unroll
    for (int i = 0; i < 4; ++i) {
      const int lin = i * 4096 + tid * 16;
      const int row = lin >> 7, byte = lin & 127;
      gl16((const char*)xT + ((size_t)(b * NnC + n0 + row) * Cc + k0) * 2 +
               (byte ^ ((row & 7) << 4)),
           (char*)&sm[buf][1][0] + lin);
    }
  };

  f32x4 acc[4][4];
#pragma unroll
  for (int i = 0; i < 4; ++i)
#pragma unroll
    for (int j = 0; j < 4; ++j) acc[i][j] = (f32x4)0.f;

  stage(0, 0);
  __syncthreads();
  for (int kt = 0; kt < 4; ++kt) {
    if (kt < 3) stage((kt + 1) & 1, (kt + 1) * 64);
    const char* A = (const char*)&sm[kt & 1][0][0];
    const char* Bm = (const char*)&sm[kt & 1][1][0];
#pragma unroll
    for (int ks = 0; ks < 2; ++ks) {
      bf16x8 af[4], bfr[4];
#pragma unroll
      for (int f = 0; f < 4; ++f) {
        const int o = oh + f * 16 + r16;
        af[f] = *(const bf16x8*)(A + ((o * 128 + ks * 64 + kg * 16) ^
                                      ((o & 7) << 4)));
        const int n = nh + f * 16 + r16;
        bfr[f] = *(const bf16x8*)(Bm + ((n * 128 + ks * 64 + kg * 16) ^
                                        ((n & 7) << 4)));
      }
#pragma unroll
      for (int fo = 0; fo < 4; ++fo)
#pragma unroll
        for (int fn = 0; fn < 4; ++fn)
          acc[fo][fn] = __builtin_amdgcn_mfma_f32_16x16x32_bf16(
              af[fo], bfr[fn], acc[fo][fn], 0, 0, 0);
    }
    __syncthreads();
  }

  // Epilogue: add bias, bounce [n][o] bf16 (swizzled) through LDS.
  const float* bias = (mt == 0) ? b_theta : (mt == 1) ? b_phi : b_g;
  u16* ldst = (u16*)&sm[0][0][0];  // [128 n][128 o] bf16, 32KB
#pragma unroll
  for (int fo = 0; fo < 4; ++fo) {
    const int obase = oh + fo * 16 + kg * 4;
    const float b0 = bias[obase], b1 = bias[obase + 1], b2 = bias[obase + 2],
                b3 = bias[obase + 3];
#pragma unroll
    for (int fn = 0; fn < 4; ++fn) {
      const int n = nh + fn * 16 + r16;
      const f32x4 v = acc[fo][fn];
      uint2 p;
      p.x = pack2(v.x + b0, v.y + b1);
      p.y = pack2(v.z + b2, v.w + b3);
      *(uint2*)((char*)ldst + ((n * 256 + obase * 2) ^ ((n & 7) << 4))) = p;
    }
  }
  __syncthreads();

  if (mt == 0) {
#pragma unroll
    for (int i = 0; i < 8; ++i) {
      const int lin = i * 4096 + tid * 16;
      const int nl = lin >> 8, byte = lin & 255;
      const uint4 v =
          *(const uint4*)((const char*)ldst + ((nl * 256 + byte) ^ ((nl & 7) << 4)));
      *(uint4*)((char*)thetaT + (size_t)(b * NnC + n0 + nl) * CiC * 2 + byte) = v;
    }
  } else if (mt == 1) {
    const int ci = tid & 127, mg = tid >> 7;
#pragma unroll
    for (int i = 0; i < 16; ++i) {
      const int mw = mg * 16 + i;
      const int n00 = 2 * mw;
      float v0 = b2f(*(const u16*)((const char*)ldst +
                                   ((n00 * 256 + ci * 2) ^ ((n00 & 7) << 4))));
      float v1 = b2f(*(const u16*)((const char*)ldst +
                                   (((n00 + 1) * 256 + ci * 2) ^ (((n00 + 1) & 7) << 4))));
      float v2 = b2f(*(const u16*)((const char*)ldst +
                                   (((n00 + 64) * 256 + ci * 2) ^ (((n00 + 64) & 7) << 4))));
      float v3 = b2f(*(const u16*)((const char*)ldst +
                                   (((n00 + 65) * 256 + ci * 2) ^ (((n00 + 65) & 7) << 4))));
      const float mx = fmaxf(fmaxf(v0, v1), fmaxf(v2, v3));
      phiT[((size_t)(b * MmC + nt * 32 + mw)) * CiC + ci] = f2b(mx);
    }
  } else {
    const int ci = tid >> 1, half = tid & 1;
#pragma unroll
    for (int i = 0; i < 16; ++i) {
      const int mw = half * 16 + i;
      const int n00 = 2 * mw;
      float v0 = b2f(*(const u16*)((const char*)ldst +
                                   ((n00 * 256 + ci * 2) ^ ((n00 & 7) << 4))));
      float v1 = b2f(*(const u16*)((const char*)ldst +
                                   (((n00 + 1) * 256 + ci * 2) ^ (((n00 + 1) & 7) << 4))));
      float v2 = b2f(*(const u16*)((const char*)ldst +
                                   (((n00 + 64) * 256 + ci * 2) ^ (((n00 + 64) & 7) << 4))));
      float v3 = b2f(*(const u16*)((const char*)ldst +
                                   (((n00 + 65) * 256 + ci * 2) ^ (((n00 + 65) & 7) << 4))));
      const float mx = fmaxf(fmaxf(v0, v1), fmaxf(v2, v3));
      gP[((size_t)(b * CiC + ci)) * MmC + nt * 32 + mw] = f2b(mx);
    }
  }
}

// ---------------------------------------------------------------------------
// attn: per (b, 128-wide n-tile): loop 64-wide m-tiles:
//   S'[m][n] = phiT[m][:] . thetaT[n][:]  (MFMA, K=128)   -> bf16 in LDS [n][m]
//   y[ci][n] += gP[ci][m-tile] . S'                        (MFMA, K=64)
// Output yT[n][ci] bf16 (scaled by 1/M) via LDS bounce. 8 waves.
// ---------------------------------------------------------------------------
__global__ __launch_bounds__(512) void attn_kernel(
    const u16* __restrict__ thetaT, const u16* __restrict__ phiT,
    const u16* __restrict__ gP, u16* __restrict__ yT) {
  __shared__ u16 thS[128 * 128];    // [n][ci] 32KB, swz ((n&7)<<4)
  __shared__ u16 phS[2][64 * 128];  // [m][ci] 16KB each
  __shared__ u16 gS[2][128 * 64];   // [ci][m] 16KB each
  __shared__ u16 SP[128 * 64];      // [n][m] 16KB
  const int nt = blockIdx.x, b = blockIdx.y;
  const int n0 = nt * 128;
  const int tid = threadIdx.x, w = tid >> 6, lane = tid & 63;
  const int r16 = lane & 15, kg = lane >> 4;

#pragma unroll
  for (int i = 0; i < 4; ++i) {
    const int lin = i * 8192 + tid * 16;
    const int nl = lin >> 8, byte = lin & 255;
    gl16((const char*)thetaT + (size_t)(b * NnC + n0 + nl) * CiC * 2 +
             (byte ^ ((nl & 7) << 4)),
         (char*)thS + lin);
  }
  auto stagePG = [&](int buf, int m0) {
#pragma unroll
    for (int i = 0; i < 2; ++i) {
      const int lin = i * 8192 + tid * 16;
      const int ml = lin >> 8, byte = lin & 255;
      gl16((const char*)phiT + (size_t)(b * MmC + m0 + ml) * CiC * 2 +
               (byte ^ ((ml & 7) << 4)),
           (char*)&phS[buf][0] + lin);
    }
#pragma unroll
    for (int i = 0; i < 2; ++i) {
      const int lin = i * 8192 + tid * 16;
      const int cil = lin >> 7, byte = lin & 127;
      gl16((const char*)gP + ((size_t)(b * CiC + cil) * MmC + m0) * 2 +
               (byte ^ ((cil & 7) << 4)),
           (char*)&gS[buf][0] + lin);
    }
  };
  stagePG(0, 0);
  __syncthreads();

  f32x4 accY[2][4];
#pragma unroll
  for (int i = 0; i < 2; ++i)
#pragma unroll
    for (int j = 0; j < 4; ++j) accY[i][j] = (f32x4)0.f;

  const int mrow = (w >> 1) * 16 + r16;   // S': wave's m-frag row
  const int nbs = (w & 1) * 64;           // S': wave's n-half
  const int mcb = (w >> 1) * 16 + kg * 4; // S' output m cols
  const int cib = (w & 3) * 32;           // y: wave's ci base
  const int nb2 = (w >> 2) * 64;          // y: wave's n-half

  for (int mi = 0; mi < 16; ++mi) {
    const int cur = mi & 1;
    if (mi < 15) stagePG(cur ^ 1, (mi + 1) * 64);
    // ---- S' phase ----
    const char* ph = (const char*)&phS[cur][0];
    f32x4 s[4];
#pragma unroll
    for (int nf = 0; nf < 4; ++nf) s[nf] = (f32x4)0.f;
#pragma unroll
    for (int ks = 0; ks < 4; ++ks) {
      const bf16x8 af = *(const bf16x8*)(ph + ((mrow * 256 + ks * 64 + kg * 16) ^
                                               ((mrow & 7) << 4)));
#pragma unroll
      for (int nf = 0; nf < 4; ++nf) {
        const int n = nbs + nf * 16 + r16;
        const bf16x8 bf_ = *(const bf16x8*)((const char*)thS +
                                            ((n * 256 + ks * 64 + kg * 16) ^
                                             ((n & 7) << 4)));
        s[nf] = __builtin_amdgcn_mfma_f32_16x16x32_bf16(af, bf_, s[nf], 0, 0, 0);
      }
    }
#pragma unroll
    for (int nf = 0; nf < 4; ++nf) {
      const int n = nbs + nf * 16 + r16;
      uint2 p;
      p.x = pack2(s[nf].x, s[nf].y);
      p.y = pack2(s[nf].z, s[nf].w);
      *(uint2*)((char*)SP + ((n * 128 + mcb * 2) ^ ((n & 7) << 4))) = p;
    }
    __syncthreads();
    // ---- y phase ----
    const char* gs = (const char*)&gS[cur][0];
#pragma unroll
    for (int ks2 = 0; ks2 < 2; ++ks2) {
      bf16x8 ga[2];
#pragma unroll
      for (int cf = 0; cf < 2; ++cf) {
        const int ci = cib + cf * 16 + r16;
        ga[cf] = *(const bf16x8*)(gs + ((ci * 128 + ks2 * 64 + kg * 16) ^
                                        ((ci & 7) << 4)));
      }
#pragma unroll
      for (int nf = 0; nf < 4; ++nf) {
        const int n = nb2 + nf * 16 + r16;
        const bf16x8 sb = *(const bf16x8*)((const char*)SP +
                                           ((n * 128 + ks2 * 64 + kg * 16) ^
                                            ((n & 7) << 4)));
#pragma unroll
        for (int cf = 0; cf < 2; ++cf)
          accY[cf][nf] = __builtin_amdgcn_mfma_f32_16x16x32_bf16(
              ga[cf], sb, accY[cf][nf], 0, 0, 0);
      }
    }
    __syncthreads();
  }

  // Epilogue: scale 1/M, bf16, bounce [n][ci] through thS, copy to yT.
  constexpr float scl = 1.f / (float)MmC;
  u16* yt = thS;
#pragma unroll
  for (int cf = 0; cf < 2; ++cf) {
    const int c0 = cib + cf * 16 + kg * 4;
#pragma unroll
    for (int nf = 0; nf < 4; ++nf) {
      const int n = nb2 + nf * 16 + r16;
      const f32x4 v = accY[cf][nf];
      uint2 p;
      p.x = pack2(v.x * scl, v.y * scl);
      p.y = pack2(v.z * scl, v.w * scl);
      *(uint2*)((char*)yt + ((n * 256 + c0 * 2) ^ ((n & 7) << 4))) = p;
    }
  }
  __syncthreads();
#pragma unroll
  for (int i = 0; i < 4; ++i) {
    const int lin = i * 8192 + tid * 16;
    const int nl = lin >> 8, byte = lin & 255;
    const uint4 v =
        *(const uint4*)((const char*)yt + ((nl * 256 + byte) ^ ((nl & 7) << 4)));
    *(uint4*)((char*)yT + (size_t)(b * NnC + n0 + nl) * CiC * 2 + byte) = v;
  }
}

// ---------------------------------------------------------------------------
// convw: out[o][n] = BN(Wwb[o][:] . yT[n][:] + b_w) + x. K=128 fully staged.
// ---------------------------------------------------------------------------
__global__ __launch_bounds__(256) void convw_kernel(
    const u16* __restrict__ yT, const u16* __restrict__ Wwb,
    const float* __restrict__ b_w, const float* __restrict__ gamma,
    const float* __restrict__ beta, const float* __restrict__ mean,
    const float* __restrict__ var, const float* __restrict__ x,
    float* __restrict__ out) {
  __shared__ u16 smA[128 * 128];  // [o][ci] 32KB
  __shared__ u16 smB[128 * 128];  // [n][ci] 32KB
  __shared__ float scs[128], offs[128];
  const int mt = blockIdx.x, nt = blockIdx.y, b = blockIdx.z;
  const int n0 = nt * 128, tid = threadIdx.x;
  const int w = tid >> 6, lane = tid & 63;
  const int r16 = lane & 15, kg = lane >> 4;
  if (tid < 128) {
    const int o = mt * 128 + tid;
    const float sc = gamma[o] * rsqrtf(var[o] + kEps);
    scs[tid] = sc;
    offs[tid] = beta[o] + (b_w[o] - mean[o]) * sc;
  }
#pragma unroll
  for (int i = 0; i < 8; ++i) {
    const int lin = i * 4096 + tid * 16;
    const int row = lin >> 8, byte = lin & 255;
    gl16((const char*)Wwb + (size_t)(mt * 128 + row) * 256 +
             (byte ^ ((row & 7) << 4)),
         (char*)smA + lin);
    gl16((const char*)yT + (size_t)(b * NnC + n0 + row) * 256 +
             (byte ^ ((row & 7) << 4)),
         (char*)smB + lin);
  }
  __syncthreads();

  f32x4 acc[4][4];
#pragma unroll
  for (int i = 0; i < 4; ++i)
#pragma unroll
    for (int j = 0; j < 4; ++j) acc[i][j] = (f32x4)0.f;
  const int oh = (w & 1) * 64, nh = (w >> 1) * 64;
#pragma unroll
  for (int ks = 0; ks < 4; ++ks) {
    bf16x8 af[4], bfr[4];
#pragma unroll
    for (int f = 0; f < 4; ++f) {
      const int o = oh + f * 16 + r16;
      af[f] = *(const bf16x8*)((const char*)smA +
                               ((o * 256 + ks * 64 + kg * 16) ^ ((o & 7) << 4)));
      const int n = nh + f * 16 + r16;
      bfr[f] = *(const bf16x8*)((const char*)smB +
                                ((n * 256 + ks * 64 + kg * 16) ^ ((n & 7) << 4)));
    }
#pragma unroll
    for (int fo = 0; fo < 4; ++fo)
#pragma unroll
      for (int fn = 0; fn < 4; ++fn)
        acc[fo][fn] = __builtin_amdgcn_mfma_f32_16x16x32_bf16(
            af[fo], bfr[fn], acc[fo][fn], 0, 0, 0);
  }

  const size_t xb = ((size_t)b * Cc + mt * 128) * NnC;
#pragma unroll
  for (int fo = 0; fo < 4; ++fo) {
#pragma unroll
    for (int r = 0; r < 4; ++r) {
      const int ol = oh + fo * 16 + kg * 4 + r;
      const float sc = scs[ol], of = offs[ol];
      const size_t rowoff = xb + (size_t)ol * NnC + n0;
#pragma unroll
      for (int fn = 0; fn < 4; ++fn) {
        const int n = nh + fn * 16 + r16;
        out[rowoff + n] = fmaf(acc[fo][fn][r], sc, of) + x[rowoff + n];
      }
    }
  }
}

// ---------------------------------------------------------------------------
extern "C" void kernel_launch(void* const* d_in, const int* in_sizes, int n_in,
                              void* d_out, int out_size, void* d_ws,
                              size_t ws_size, hipStream_t stream) {
  const float* x = (const float*)d_in[0];
  const float* w_theta = (const float*)d_in[1];
  const float* b_theta = (const float*)d_in[2];
  const float* w_phi = (const float*)d_in[3];
  const float* b_phi = (const float*)d_in[4];
  const float* w_g = (const float*)d_in[5];
  const float* b_g = (const float*)d_in[6];
  const float* w_w = (const float*)d_in[7];
  const float* b_w = (const float*)d_in[8];
  const float* bn_gamma = (const float*)d_in[9];
  const float* bn_beta = (const float*)d_in[10];
  const float* bn_mean = (const float*)d_in[11];
  const float* bn_var = (const float*)d_in[12];
  float* out = (float*)d_out;

  char* ws = (char*)d_ws;
  u16* xT = (u16*)ws;
  u16* thetaT = (u16*)(ws + 16777216);
  u16* phiT = (u16*)(ws + 25165824);
  u16* gP = (u16*)(ws + 27262976);
  u16* yT = (u16*)(ws + 29360128);
  u16* W3b = (u16*)(ws + 37748736);
  u16* Wwb = (u16*)(ws + 37945344);
  if (ws_size < 38010880ull) return;

  prepw_kernel<<<dim3(512), dim3(256), 0, stream>>>(w_theta, w_phi, w_g, w_w,
                                                    W3b, Wwb);
  prepx_kernel<<<dim3(64, 4, 8), dim3(256), 0, stream>>>(x, xT);
  conv3_kernel<<<dim3(3, 32, 8), dim3(256), 0, stream>>>(
      xT, W3b, b_theta, b_phi, b_g, thetaT, phiT, gP);
  attn_kernel<<<dim3(32, 8), dim3(512), 0, stream>>>(thetaT, phiT, gP, yT);
  convw_kernel<<<dim3(2, 32, 8), dim3(256), 0, stream>>>(
      yT, Wwb, b_w, bn_gamma, bn_beta, bn_mean, bn_var, x, out);
}

// Round 4
// 157.567 us; speedup vs baseline: 4.2695x; 1.0469x over previous
//
#include <hip/hip_runtime.h>

// NonLocalBlockND, algebraically collapsed (linear attention, no softmax):
//   A[b]    = g_p[b] . phi_p[b]^T / M                  [128,128]
//   W_big[b]= W_w . A[b] . W_theta                     [256,256]
//   b_eff[b]= W_w . (A[b] . b_theta) + b_w             [256]
//   out     = BN(W_big[b] . x + b_eff[b]) + x
// phi_p/g_p are pooled conv outputs (pooling is the only nonlinearity).
//
// ws layout (bytes):
//   xT   [8][4096][256] bf16 @ 0          (16,777,216)
//   Wfg  [256][256]     bf16 @ 16777216   (   131,072)  rows 0-127 phi,128-255 g
//   phiT [8][128][1024] bf16 @ 16908288   ( 2,097,152)  pooled, [ci][m]
//   gT   [8][128][1024] bf16 @ 19005440   ( 2,097,152)  pooled, [ci][m]
//   A_g2 [8][128][128]  f32  @ 21102592   (   524,288)
//   T1   [8][128][256]  f32  @ 21626880   ( 1,048,576)
//   Wbig [8][256][256]  bf16 @ 22675456   ( 1,048,576)
//   beff [8][256]       f32  @ 23724032   (     8,192)
// total 23,732,224 B

typedef __attribute__((ext_vector_type(8))) short bf16x8;
typedef __attribute__((ext_vector_type(4))) float f32x4;
typedef unsigned short u16;
typedef unsigned int u32;

constexpr int Cc = 256, NnC = 4096;
constexpr float kEps = 1e-5f;

__device__ __forceinline__ u16 f2b(float f) {
  u32 u = __float_as_uint(f);
  return (u16)((u + 0x7fffu + ((u >> 16) & 1u)) >> 16);
}
__device__ __forceinline__ float b2f(u16 h) {
  return __uint_as_float(((u32)h) << 16);
}
__device__ __forceinline__ u32 pack2(float a, float b) {
  return (u32)f2b(a) | ((u32)f2b(b) << 16);
}
__device__ __forceinline__ void gl16(const void* g, void* l) {
  __builtin_amdgcn_global_load_lds(
      (const __attribute__((address_space(1))) void*)g,
      (__attribute__((address_space(3))) void*)l, 16, 0, 0);
}

// ---------------------------------------------------------------------------
// prepw: stacked phi/g conv weights -> bf16 [256][256]
// ---------------------------------------------------------------------------
__global__ __launch_bounds__(256) void prepw_kernel(
    const float* __restrict__ wp, const float* __restrict__ wg,
    u16* __restrict__ Wfg) {
  const int idx = blockIdx.x * 256 + threadIdx.x;  // 65536
  const int r = idx >> 8, c = idx & 255;
  Wfg[idx] = f2b(r < 128 ? wp[r * 256 + c] : wg[(r - 128) * 256 + c]);
}

// ---------------------------------------------------------------------------
// prepx: transpose x [b][c][n] f32 -> xT [b][n][c] bf16 via LDS tile.
// ---------------------------------------------------------------------------
__global__ __launch_bounds__(256) void prepx_kernel(const float* __restrict__ x,
                                                    u16* __restrict__ xT) {
  __shared__ float sm[64][65];
  const int b = blockIdx.z, c0 = blockIdx.y * 64, n0 = blockIdx.x * 64;
  const int tid = threadIdx.x;
  {
    const int n = tid & 63, cg = tid >> 6;
#pragma unroll
    for (int i = 0; i < 16; ++i) {
      const int c = cg * 16 + i;
      sm[c][n] = x[((size_t)(b * Cc + c0 + c)) * NnC + n0 + n];
    }
  }
  __syncthreads();
  {
    const int n = tid >> 2, q = tid & 3;
    u16 v[16];
#pragma unroll
    for (int j = 0; j < 16; ++j) v[j] = f2b(sm[q * 16 + j][n]);
    uint4 o0, o1;
    o0.x = v[0] | ((u32)v[1] << 16);
    o0.y = v[2] | ((u32)v[3] << 16);
    o0.z = v[4] | ((u32)v[5] << 16);
    o0.w = v[6] | ((u32)v[7] << 16);
    o1.x = v[8] | ((u32)v[9] << 16);
    o1.y = v[10] | ((u32)v[11] << 16);
    o1.z = v[12] | ((u32)v[13] << 16);
    o1.w = v[14] | ((u32)v[15] << 16);
    uint4* dst = (uint4*)(xT + ((size_t)(b * NnC + n0 + n)) * Cc + c0 + q * 16);
    dst[0] = o0;
    dst[1] = o1;
  }
}

// ---------------------------------------------------------------------------
// convfg: D[o][n] = Wfg[mt*128+o][:] . xT[n][:] (K=256), 128x128 tile, 4 waves.
// Epilogue: +bias, 2x2 maxpool, write [ci][m] to phiT (mt=0) or gT (mt=1).
// n-tile 128 covers h in {2nt,2nt+1}, w 0..63 -> pooled m = nt*32 + wm.
// ---------------------------------------------------------------------------
__global__ __launch_bounds__(256) void convfg_kernel(
    const u16* __restrict__ xT, const u16* __restrict__ Wfg,
    const float* __restrict__ b_phi, const float* __restrict__ b_g,
    u16* __restrict__ phiT, u16* __restrict__ gT) {
  __shared__ u16 sm[2][2][8192];  // [buf][A/B][128 rows][64 k] bf16
  const int mt = blockIdx.x, nt = blockIdx.y, b = blockIdx.z;
  const int n0 = nt * 128;
  const int tid = threadIdx.x;
  const int w = tid >> 6, lane = tid & 63;
  const int r16 = lane & 15, kg = lane >> 4;
  const int oh = (w & 1) * 64, nh = (w >> 1) * 64;

  auto stage = [&](int buf, int k0) {
#pragma unroll
    for (int i = 0; i < 4; ++i) {
      const int lin = i * 4096 + tid * 16;
      const int row = lin >> 7, byte = lin & 127;
      gl16((const char*)Wfg + (size_t)(mt * 128 + row) * 512 + k0 * 2 +
               (byte ^ ((row & 7) << 4)),
           (char*)&sm[buf][0][0] + lin);
    }
#pragma unroll
    for (int i = 0; i < 4; ++i) {
      const int lin = i * 4096 + tid * 16;
      const int row = lin >> 7, byte = lin & 127;
      gl16((const char*)xT + ((size_t)(b * NnC + n0 + row) * Cc + k0) * 2 +
               (byte ^ ((row & 7) << 4)),
           (char*)&sm[buf][1][0] + lin);
    }
  };

  f32x4 acc[4][4];
#pragma unroll
  for (int i = 0; i < 4; ++i)
#pragma unroll
    for (int j = 0; j < 4; ++j) acc[i][j] = (f32x4)0.f;

  stage(0, 0);
  __syncthreads();
  for (int kt = 0; kt < 4; ++kt) {
    if (kt < 3) stage((kt + 1) & 1, (kt + 1) * 64);
    const char* A = (const char*)&sm[kt & 1][0][0];
    const char* Bm = (const char*)&sm[kt & 1][1][0];
#pragma unroll
    for (int ks = 0; ks < 2; ++ks) {
      bf16x8 af[4], bfr[4];
#pragma unroll
      for (int f = 0; f < 4; ++f) {
        const int o = oh + f * 16 + r16;
        af[f] = *(const bf16x8*)(A + ((o * 128 + ks * 64 + kg * 16) ^
                                      ((o & 7) << 4)));
        const int n = nh + f * 16 + r16;
        bfr[f] = *(const bf16x8*)(Bm + ((n * 128 + ks * 64 + kg * 16) ^
                                        ((n & 7) << 4)));
      }
#pragma unroll
      for (int fo = 0; fo < 4; ++fo)
#pragma unroll
        for (int fn = 0; fn < 4; ++fn)
          acc[fo][fn] = __builtin_amdgcn_mfma_f32_16x16x32_bf16(
              af[fo], bfr[fn], acc[fo][fn], 0, 0, 0);
    }
    __syncthreads();
  }

  // Epilogue: bias, bounce [n][o] bf16 through LDS, pool, write [ci][m].
  const float* bias = (mt == 0) ? b_phi : b_g;
  u16* ldst = (u16*)&sm[0][0][0];  // [128 n][128 o] bf16, swizzled
#pragma unroll
  for (int fo = 0; fo < 4; ++fo) {
    const int obase = oh + fo * 16 + kg * 4;
    const float b0 = bias[obase], b1 = bias[obase + 1], b2 = bias[obase + 2],
                b3 = bias[obase + 3];
#pragma unroll
    for (int fn = 0; fn < 4; ++fn) {
      const int n = nh + fn * 16 + r16;
      const f32x4 v = acc[fo][fn];
      uint2 p;
      p.x = pack2(v.x + b0, v.y + b1);
      p.y = pack2(v.z + b2, v.w + b3);
      *(uint2*)((char*)ldst + ((n * 256 + obase * 2) ^ ((n & 7) << 4))) = p;
    }
  }
  __syncthreads();

  u16* dst = (mt == 0) ? phiT : gT;
  const int ci = tid >> 1, half = tid & 1;
#pragma unroll
  for (int i = 0; i < 16; ++i) {
    const int mw = half * 16 + i;
    const int n00 = 2 * mw;
    float v0 = b2f(*(const u16*)((const char*)ldst +
                                 ((n00 * 256 + ci * 2) ^ ((n00 & 7) << 4))));
    float v1 = b2f(*(const u16*)((const char*)ldst +
                                 (((n00 + 1) * 256 + ci * 2) ^ (((n00 + 1) & 7) << 4))));
    float v2 = b2f(*(const u16*)((const char*)ldst +
                                 (((n00 + 64) * 256 + ci * 2) ^ (((n00 + 64) & 7) << 4))));
    float v3 = b2f(*(const u16*)((const char*)ldst +
                                 (((n00 + 65) * 256 + ci * 2) ^ (((n00 + 65) & 7) << 4))));
    const float mx = fmaxf(fmaxf(v0, v1), fmaxf(v2, v3));
    dst[((size_t)(b * 128 + ci)) * 1024 + nt * 32 + mw] = f2b(mx);
  }
}

// ---------------------------------------------------------------------------
// g2: A_g2[b][ci][c] = (1/M) sum_m gT[b][ci][m] * phiT[b][c][m].  K=1024.
// grid (2 c-halves, 8 b), 4 waves, 64-m chunks double-buffered.
// LDS per buffer: A = 128 rows x 128 B = 16384 B (u16 idx [0,8192)),
//                 B =  64 rows x 128 B =  8192 B (u16 idx [8192,12288)).
// ---------------------------------------------------------------------------
__global__ __launch_bounds__(256) void g2_kernel(const u16* __restrict__ phiT,
                                                 const u16* __restrict__ gT,
                                                 float* __restrict__ A_g2) {
  __shared__ u16 sm[2][12288];
  const int ch0 = blockIdx.x * 64, b = blockIdx.y;
  const int tid = threadIdx.x;
  const int w = tid >> 6, lane = tid & 63;
  const int r16 = lane & 15, kg = lane >> 4;
  const int cih = (w & 1) * 64, cch = (w >> 1) * 32;

  auto stage = [&](int buf, int m0) {
#pragma unroll
    for (int i = 0; i < 4; ++i) {
      const int lin = i * 4096 + tid * 16;
      const int row = lin >> 7, byte = lin & 127;
      gl16((const char*)gT + ((size_t)(b * 128 + row) * 1024 + m0) * 2 +
               (byte ^ ((row & 7) << 4)),
           (char*)&sm[buf][0] + lin);
    }
#pragma unroll
    for (int i = 0; i < 2; ++i) {
      const int lin = i * 4096 + tid * 16;
      const int row = lin >> 7, byte = lin & 127;
      gl16((const char*)phiT + ((size_t)(b * 128 + ch0 + row) * 1024 + m0) * 2 +
               (byte ^ ((row & 7) << 4)),
           (char*)&sm[buf][8192] + lin);  // B region at byte 16384
    }
  };

  f32x4 acc[4][2];
#pragma unroll
  for (int i = 0; i < 4; ++i)
#pragma unroll
    for (int j = 0; j < 2; ++j) acc[i][j] = (f32x4)0.f;

  stage(0, 0);
  __syncthreads();
  for (int kt = 0; kt < 16; ++kt) {
    if (kt < 15) stage((kt + 1) & 1, (kt + 1) * 64);
    const char* A = (const char*)&sm[kt & 1][0];
    const char* Bp = A + 16384;  // matches B staging region
#pragma unroll
    for (int ks = 0; ks < 2; ++ks) {
      bf16x8 af[4], bfr[2];
#pragma unroll
      for (int f = 0; f < 4; ++f) {
        const int o = cih + f * 16 + r16;
        af[f] = *(const bf16x8*)(A + ((o * 128 + ks * 64 + kg * 16) ^
                                      ((o & 7) << 4)));
      }
#pragma unroll
      for (int f = 0; f < 2; ++f) {
        const int lc = cch + f * 16 + r16;
        bfr[f] = *(const bf16x8*)(Bp + ((lc * 128 + ks * 64 + kg * 16) ^
                                        ((lc & 7) << 4)));
      }
#pragma unroll
      for (int fo = 0; fo < 4; ++fo)
#pragma unroll
        for (int fn = 0; fn < 2; ++fn)
          acc[fo][fn] = __builtin_amdgcn_mfma_f32_16x16x32_bf16(
              af[fo], bfr[fn], acc[fo][fn], 0, 0, 0);
    }
    __syncthreads();
  }

  constexpr float scl = 1.f / 1024.f;
#pragma unroll
  for (int fo = 0; fo < 4; ++fo) {
#pragma unroll
    for (int r = 0; r < 4; ++r) {
      const int ci = cih + fo * 16 + kg * 4 + r;
#pragma unroll
      for (int fn = 0; fn < 2; ++fn) {
        const int c = ch0 + cch + fn * 16 + r16;
        A_g2[(size_t)b * 16384 + ci * 128 + c] = acc[fo][fn][r] * scl;
      }
    }
  }
}

// ---------------------------------------------------------------------------
// t1: T1[b][ci][j] = sum_c A_g2[b][ci][c] * w_theta[c][j].  fp32, tiny.
// ---------------------------------------------------------------------------
__global__ __launch_bounds__(256) void t1_kernel(const float* __restrict__ A_g2,
                                                 const float* __restrict__ w_theta,
                                                 float* __restrict__ T1) {
  __shared__ float As[16][128];
  __shared__ float Ws[128][17];
  const int tile = blockIdx.x, b = blockIdx.y;
  const int ci0 = (tile >> 4) * 16, j0 = (tile & 15) * 16;
  const int t = threadIdx.x;
#pragma unroll
  for (int i = 0; i < 8; ++i) {
    const int idx = t + i * 256;
    As[idx >> 7][idx & 127] =
        A_g2[(size_t)b * 16384 + (ci0 + (idx >> 7)) * 128 + (idx & 127)];
    Ws[idx >> 4][idx & 15] = w_theta[(idx >> 4) * 256 + j0 + (idx & 15)];
  }
  __syncthreads();
  const int tci = t >> 4, tj = t & 15;
  float s = 0.f;
#pragma unroll 8
  for (int c = 0; c < 128; ++c) s = fmaf(As[tci][c], Ws[c][tj], s);
  T1[(size_t)b * 32768 + (ci0 + tci) * 256 + j0 + tj] = s;
}

// ---------------------------------------------------------------------------
// wbig: Wbig[b][o][j] = bf16( sum_ci w_w[o][ci] * T1[b][ci][j] )
// tile 256: beff[b][o] = w_w[o][:] . (A_g2[b] . b_theta) + b_w[o]
// ---------------------------------------------------------------------------
__global__ __launch_bounds__(256) void wbig_kernel(
    const float* __restrict__ T1, const float* __restrict__ A_g2,
    const float* __restrict__ w_w, const float* __restrict__ b_theta,
    const float* __restrict__ b_w, u16* __restrict__ Wbig,
    float* __restrict__ beff) {
  __shared__ float Ws2[16][128];
  __shared__ float T1s[128][17];
  __shared__ float v1[128];
  const int tile = blockIdx.x, b = blockIdx.y;
  const int t = threadIdx.x;
  if (tile < 256) {
    const int o0 = (tile >> 4) * 16, j0 = (tile & 15) * 16;
#pragma unroll
    for (int i = 0; i < 8; ++i) {
      const int idx = t + i * 256;
      Ws2[idx >> 7][idx & 127] = w_w[(o0 + (idx >> 7)) * 128 + (idx & 127)];
      T1s[idx >> 4][idx & 15] =
          T1[(size_t)b * 32768 + (idx >> 4) * 256 + j0 + (idx & 15)];
    }
    __syncthreads();
    const int to = t >> 4, tj = t & 15;
    float s = 0.f;
#pragma unroll 8
    for (int c = 0; c < 128; ++c) s = fmaf(Ws2[to][c], T1s[c][tj], s);
    Wbig[(size_t)b * 65536 + (o0 + to) * 256 + j0 + tj] = f2b(s);
  } else {
    if (t < 128) {
      float s = 0.f;
      for (int c = 0; c < 128; ++c)
        s = fmaf(A_g2[(size_t)b * 16384 + t * 128 + c], b_theta[c], s);
      v1[t] = s;
    }
    __syncthreads();
    float s2 = b_w[t];
    for (int ci = 0; ci < 128; ++ci) s2 = fmaf(w_w[t * 128 + ci], v1[ci], s2);
    beff[b * 256 + t] = s2;
  }
}

// ---------------------------------------------------------------------------
// final: out[b][o][n] = BN(Wbig[b][o][:] . xT[n][:] + beff) + x.  K=256.
// ---------------------------------------------------------------------------
__global__ __launch_bounds__(256) void final_kernel(
    const u16* __restrict__ xT, const u16* __restrict__ Wbig,
    const float* __restrict__ beff, const float* __restrict__ gamma,
    const float* __restrict__ beta, const float* __restrict__ mean,
    const float* __restrict__ var, const float* __restrict__ x,
    float* __restrict__ out) {
  __shared__ u16 sm[2][2][8192];
  __shared__ float scs[128], offs[128];
  const int mt = blockIdx.x, nt = blockIdx.y, b = blockIdx.z;
  const int n0 = nt * 128;
  const int tid = threadIdx.x;
  const int w = tid >> 6, lane = tid & 63;
  const int r16 = lane & 15, kg = lane >> 4;
  const int oh = (w & 1) * 64, nh = (w >> 1) * 64;

  if (tid < 128) {
    const int o = mt * 128 + tid;
    const float sc = gamma[o] * rsqrtf(var[o] + kEps);
    scs[tid] = sc;
    offs[tid] = beta[o] + (beff[b * 256 + o] - mean[o]) * sc;
  }

  auto stage = [&](int buf, int k0) {
#pragma unroll
    for (int i = 0; i < 4; ++i) {
      const int lin = i * 4096 + tid * 16;
      const int row = lin >> 7, byte = lin & 127;
      gl16((const char*)Wbig + (size_t)b * 131072 +
               (size_t)(mt * 128 + row) * 512 + k0 * 2 +
               (byte ^ ((row & 7) << 4)),
           (char*)&sm[buf][0][0] + lin);
    }
#pragma unroll
    for (int i = 0; i < 4; ++i) {
      const int lin = i * 4096 + tid * 16;
      const int row = lin >> 7, byte = lin & 127;
      gl16((const char*)xT + ((size_t)(b * NnC + n0 + row) * Cc + k0) * 2 +
               (byte ^ ((row & 7) << 4)),
           (char*)&sm[buf][1][0] + lin);
    }
  };

  f32x4 acc[4][4];
#pragma unroll
  for (int i = 0; i < 4; ++i)
#pragma unroll
    for (int j = 0; j < 4; ++j) acc[i][j] = (f32x4)0.f;

  stage(0, 0);
  __syncthreads();
  for (int kt = 0; kt < 4; ++kt) {
    if (kt < 3) stage((kt + 1) & 1, (kt + 1) * 64);
    const char* A = (const char*)&sm[kt & 1][0][0];
    const char* Bm = (const char*)&sm[kt & 1][1][0];
#pragma unroll
    for (int ks = 0; ks < 2; ++ks) {
      bf16x8 af[4], bfr[4];
#pragma unroll
      for (int f = 0; f < 4; ++f) {
        const int o = oh + f * 16 + r16;
        af[f] = *(const bf16x8*)(A + ((o * 128 + ks * 64 + kg * 16) ^
                                      ((o & 7) << 4)));
        const int n = nh + f * 16 + r16;
        bfr[f] = *(const bf16x8*)(Bm + ((n * 128 + ks * 64 + kg * 16) ^
                                        ((n & 7) << 4)));
      }
#pragma unroll
      for (int fo = 0; fo < 4; ++fo)
#pragma unroll
        for (int fn = 0; fn < 4; ++fn)
          acc[fo][fn] = __builtin_amdgcn_mfma_f32_16x16x32_bf16(
              af[fo], bfr[fn], acc[fo][fn], 0, 0, 0);
    }
    __syncthreads();
  }

  const size_t xb = ((size_t)b * Cc + mt * 128) * NnC;
#pragma unroll
  for (int fo = 0; fo < 4; ++fo) {
#pragma unroll
    for (int r = 0; r < 4; ++r) {
      const int ol = oh + fo * 16 + kg * 4 + r;
      const float sc = scs[ol], of = offs[ol];
      const size_t rowoff = xb + (size_t)ol * NnC + n0;
#pragma unroll
      for (int fn = 0; fn < 4; ++fn) {
        const int n = nh + fn * 16 + r16;
        out[rowoff + n] = fmaf(acc[fo][fn][r], sc, of) + x[rowoff + n];
      }
    }
  }
}

// ---------------------------------------------------------------------------
extern "C" void kernel_launch(void* const* d_in, const int* in_sizes, int n_in,
                              void* d_out, int out_size, void* d_ws,
                              size_t ws_size, hipStream_t stream) {
  const float* x = (const float*)d_in[0];
  const float* w_theta = (const float*)d_in[1];
  const float* b_theta = (const float*)d_in[2];
  const float* w_phi = (const float*)d_in[3];
  const float* b_phi = (const float*)d_in[4];
  const float* w_g = (const float*)d_in[5];
  const float* b_g = (const float*)d_in[6];
  const float* w_w = (const float*)d_in[7];
  const float* b_w = (const float*)d_in[8];
  const float* bn_gamma = (const float*)d_in[9];
  const float* bn_beta = (const float*)d_in[10];
  const float* bn_mean = (const float*)d_in[11];
  const float* bn_var = (const float*)d_in[12];
  float* out = (float*)d_out;

  char* ws = (char*)d_ws;
  u16* xT = (u16*)ws;
  u16* Wfg = (u16*)(ws + 16777216);
  u16* phiT = (u16*)(ws + 16908288);
  u16* gT = (u16*)(ws + 19005440);
  float* A_g2 = (float*)(ws + 21102592);
  float* T1 = (float*)(ws + 21626880);
  u16* Wbig = (u16*)(ws + 22675456);
  float* beff = (float*)(ws + 23724032);
  if (ws_size < 23732224ull) return;

  prepw_kernel<<<dim3(256), dim3(256), 0, stream>>>(w_phi, w_g, Wfg);
  prepx_kernel<<<dim3(64, 4, 8), dim3(256), 0, stream>>>(x, xT);
  convfg_kernel<<<dim3(2, 32, 8), dim3(256), 0, stream>>>(
      xT, Wfg, b_phi, b_g, phiT, gT);
  g2_kernel<<<dim3(2, 8), dim3(256), 0, stream>>>(phiT, gT, A_g2);
  t1_kernel<<<dim3(128, 8), dim3(256), 0, stream>>>(A_g2, w_theta, T1);
  wbig_kernel<<<dim3(257, 8), dim3(256), 0, stream>>>(T1, A_g2, w_w, b_theta,
                                                      b_w, Wbig, beff);
  final_kernel<<<dim3(2, 32, 8), dim3(256), 0, stream>>>(
      xT, Wbig, beff, bn_gamma, bn_beta, bn_mean, bn_var, x, out);
}